// Round 1
// baseline (394.340 us; speedup 1.0000x reference)
//
#include <hip/hip_runtime.h>
#include <hip/hip_bf16.h>

#define N_EDGES 500000
#define N_NODES 50000
#define LN_EPS 1e-5f

typedef __attribute__((ext_vector_type(8))) short bf16x8;
typedef __attribute__((ext_vector_type(4))) float f32x4;

static __device__ __forceinline__ short f2bf(float f) {
  unsigned u = __builtin_bit_cast(unsigned, f);
  u += 0x7fffu + ((u >> 16) & 1u);  // round-to-nearest-even
  return (short)(u >> 16);
}

// Convert W1 [384,128] -> W1^T bf16 [128 n][384 k]; W2 [128,128] -> W2^T bf16 [128 n][128 k]
__global__ void convert_weights_kernel(const float* __restrict__ W1,
                                       const float* __restrict__ W2,
                                       short* __restrict__ w1t,
                                       short* __restrict__ w2t) {
  int i = blockIdx.x * blockDim.x + threadIdx.x;
  if (i < 384 * 128) {
    int n = i / 384, k = i - n * 384;
    w1t[i] = f2bf(W1[k * 128 + n]);
  }
  if (i < 128 * 128) {
    int n = i >> 7, k = i & 127;
    w2t[i] = f2bf(W2[k * 128 + n]);
  }
}

// One block = 4 waves = 128 edges. Wave w owns rows [w*32, w*32+32).
// GEMM1: A (gathered concat feats, fp32->bf16 in-reg) x W1t -> H[128]
// SiLU -> LDS (XOR-swizzled) -> GEMM2 x W2t -> LayerNorm -> +efeat -> out
__global__ __launch_bounds__(256, 2) void edge_mlp_kernel(
    const float* __restrict__ efeat, const float* __restrict__ nfeat,
    const int* __restrict__ src, const int* __restrict__ dst,
    const short* __restrict__ w1t, const short* __restrict__ w2t,
    const float* __restrict__ b1, const float* __restrict__ b2,
    const float* __restrict__ gamma, const float* __restrict__ beta,
    float* __restrict__ out) {
  __shared__ short Hlds[128 * 128];  // 32 KB bf16, swizzled

  const int lane = threadIdx.x & 63;
  const int wave = threadIdx.x >> 6;
  const int lrow = lane & 15;   // A-frag row / C-frag col
  const int kgrp = lane >> 4;   // 0..3: k-offset group
  const int rbase = wave * 32;
  const int ebase = blockIdx.x * 128;

  // Per-lane row pointers for the 3 concat segments (k 0-127 / 128-255 / 256-383)
  const float* pA[2][3];
#pragma unroll
  for (int m = 0; m < 2; ++m) {
    int e = ebase + rbase + m * 16 + lrow;
    int ec = e < N_EDGES ? e : (N_EDGES - 1);
    pA[m][0] = efeat + (size_t)ec * 128;
    pA[m][1] = nfeat + (size_t)src[ec] * 128;
    pA[m][2] = nfeat + (size_t)dst[ec] * 128;
  }

  f32x4 acc[2][8];
#pragma unroll
  for (int m = 0; m < 2; ++m)
#pragma unroll
    for (int n = 0; n < 8; ++n) acc[m][n] = (f32x4)0.f;

  // ---- GEMM1: K = 384, 12 K-steps of 32 ----
#pragma unroll
  for (int ks = 0; ks < 12; ++ks) {
    const int seg = ks >> 2;
    const int kloc = (ks & 3) * 32 + kgrp * 8;  // within-segment k offset for this lane
    bf16x8 a[2];
#pragma unroll
    for (int m = 0; m < 2; ++m) {
      const float* p = pA[m][seg] + kloc;
      f32x4 lo = *(const f32x4*)p;
      f32x4 hi = *(const f32x4*)(p + 4);
      bf16x8 t;
#pragma unroll
      for (int j = 0; j < 4; ++j) { t[j] = f2bf(lo[j]); t[4 + j] = f2bf(hi[j]); }
      a[m] = t;
    }
    const int k0 = ks * 32 + kgrp * 8;
#pragma unroll
    for (int n = 0; n < 8; ++n) {
      bf16x8 b = *(const bf16x8*)(w1t + (n * 16 + lrow) * 384 + k0);
#pragma unroll
      for (int m = 0; m < 2; ++m)
        acc[m][n] = __builtin_amdgcn_mfma_f32_16x16x32_bf16(a[m], b, acc[m][n], 0, 0, 0);
    }
  }

  // ---- bias1 + SiLU -> LDS (bf16, XOR swizzle byte^=(row&7)<<4) ----
  float b1v[8];
#pragma unroll
  for (int n = 0; n < 8; ++n) b1v[n] = b1[n * 16 + lrow];

  char* hb = (char*)Hlds;
#pragma unroll
  for (int m = 0; m < 2; ++m)
#pragma unroll
    for (int n = 0; n < 8; ++n)
#pragma unroll
      for (int r = 0; r < 4; ++r) {
        float x = acc[m][n][r] + b1v[n];
        float h = x / (1.f + __expf(-x));  // SiLU
        int row = rbase + m * 16 + kgrp * 4 + r;  // C/D: row=(lane>>4)*4+reg
        int col = n * 16 + lrow;                  // C/D: col=lane&15
        int byte = ((row << 8) + (col << 1)) ^ ((row & 7) << 4);
        *(short*)(hb + byte) = f2bf(h);
      }
  __syncthreads();

  // ---- GEMM2: K = 128, 4 K-steps of 32, A from LDS ----
  f32x4 acc2[2][8];
#pragma unroll
  for (int m = 0; m < 2; ++m)
#pragma unroll
    for (int n = 0; n < 8; ++n) acc2[m][n] = (f32x4)0.f;

#pragma unroll
  for (int ks = 0; ks < 4; ++ks) {
    bf16x8 a2[2];
#pragma unroll
    for (int m = 0; m < 2; ++m) {
      int row = rbase + m * 16 + lrow;
      int byte = ((row << 8) + ((ks * 32 + kgrp * 8) << 1)) ^ ((row & 7) << 4);
      a2[m] = *(const bf16x8*)(hb + byte);
    }
#pragma unroll
    for (int n = 0; n < 8; ++n) {
      bf16x8 b = *(const bf16x8*)(w2t + (n * 16 + lrow) * 128 + ks * 32 + kgrp * 8);
#pragma unroll
      for (int m = 0; m < 2; ++m)
        acc2[m][n] = __builtin_amdgcn_mfma_f32_16x16x32_bf16(a2[m], b, acc2[m][n], 0, 0, 0);
    }
  }

  // ---- bias2 + LayerNorm (per edge-row, 16-lane group reduce) + residual + store ----
  float b2v[8], gv[8], bev[8];
#pragma unroll
  for (int n = 0; n < 8; ++n) {
    int c = n * 16 + lrow;
    b2v[n] = b2[c];
    gv[n] = gamma[c];
    bev[n] = beta[c];
  }

#pragma unroll
  for (int m = 0; m < 2; ++m) {
    float s1[4], s2[4];
#pragma unroll
    for (int r = 0; r < 4; ++r) { s1[r] = 0.f; s2[r] = 0.f; }
#pragma unroll
    for (int n = 0; n < 8; ++n)
#pragma unroll
      for (int r = 0; r < 4; ++r) {
        float x = acc2[m][n][r] + b2v[n];
        s1[r] += x;
        s2[r] += x * x;
      }
    // rows live in 16-lane groups (same kgrp) -> xor-reduce over offsets 1,2,4,8
#pragma unroll
    for (int off = 1; off < 16; off <<= 1)
#pragma unroll
      for (int r = 0; r < 4; ++r) {
        s1[r] += __shfl_xor(s1[r], off, 64);
        s2[r] += __shfl_xor(s2[r], off, 64);
      }
#pragma unroll
    for (int r = 0; r < 4; ++r) {
      int e = ebase + rbase + m * 16 + kgrp * 4 + r;
      if (e < N_EDGES) {
        float mu = s1[r] * (1.f / 128.f);
        float var = s2[r] * (1.f / 128.f) - mu * mu;
        float rs = rsqrtf(var + LN_EPS);
        const float* er = efeat + (size_t)e * 128;
        float* orow = out + (size_t)e * 128;
#pragma unroll
        for (int n = 0; n < 8; ++n) {
          float x = acc2[m][n][r] + b2v[n];
          orow[n * 16 + lrow] = (x - mu) * rs * gv[n] + bev[n] + er[n * 16 + lrow];
        }
      }
    }
  }
}

extern "C" void kernel_launch(void* const* d_in, const int* in_sizes, int n_in,
                              void* d_out, int out_size, void* d_ws, size_t ws_size,
                              hipStream_t stream) {
  const float* efeat = (const float*)d_in[0];
  const float* nfeat = (const float*)d_in[1];
  const int* src = (const int*)d_in[2];
  const int* dst = (const int*)d_in[3];
  const float* W1 = (const float*)d_in[4];
  const float* b1 = (const float*)d_in[5];
  const float* W2 = (const float*)d_in[6];
  const float* b2 = (const float*)d_in[7];
  const float* gamma = (const float*)d_in[8];
  const float* beta = (const float*)d_in[9];
  float* out = (float*)d_out;

  short* w1t = (short*)d_ws;              // 384*128 bf16 = 96 KB
  short* w2t = w1t + 384 * 128;           // 128*128 bf16 = 32 KB

  // nfeat passthrough (second tuple element)
  hipMemcpyAsync(out + (size_t)N_EDGES * 128, nfeat,
                 (size_t)N_NODES * 128 * sizeof(float),
                 hipMemcpyDeviceToDevice, stream);

  convert_weights_kernel<<<192, 256, 0, stream>>>(W1, W2, w1t, w2t);

  const int nblocks = (N_EDGES + 127) / 128;  // 3907
  edge_mlp_kernel<<<nblocks, 256, 0, stream>>>(efeat, nfeat, src, dst, w1t, w2t,
                                               b1, b2, gamma, beta, out);
}